// Round 6
// baseline (1219.465 us; speedup 1.0000x reference)
//
#include <hip/hip_runtime.h>
#include <math.h>

#define B_   32
#define L_   1024
#define C_   32
#define D_   512
#define SEG_ 16
#define SX_  64
#define N_   1024   // B*C

typedef _Float16 f16x8 __attribute__((ext_vector_type(8)));
typedef _Float16 f16x4 __attribute__((ext_vector_type(4)));
typedef float    f32x4 __attribute__((ext_vector_type(4)));

__device__ __forceinline__ void stage16(const void* g, void* l) {
    __builtin_amdgcn_global_load_lds((const __attribute__((address_space(1))) void*)g,
                                     (__attribute__((address_space(3))) void*)l, 16, 0, 0);
}

// ---------------------------------------------------------------------------
// prep: x (B,L,C) -> xs_seg, xt_seg fp32 (step, n, seg); channel-axis moving
// mean (reference semantics), window 25, edge replication.
// ---------------------------------------------------------------------------
__global__ __launch_bounds__(256) void prep_kernel(const float* __restrict__ x,
                                                   float* __restrict__ xs_seg,
                                                   float* __restrict__ xt_seg) {
    int b = blockIdx.x >> 2;
    int t = ((blockIdx.x & 3) << 8) + threadIdx.x;
    const float* xb    = x + (size_t)b * (L_ * C_);
    const float* xrow  = xb + (size_t)t * C_;
    const float* xlast = xb + (size_t)(L_ - 1) * C_;

    float diff[C_];
#pragma unroll
    for (int c = 0; c < C_; ++c) diff[c] = xrow[c] - xlast[c];
    float ps[C_ + 1];
    ps[0] = 0.f;
#pragma unroll
    for (int c = 0; c < C_; ++c) ps[c + 1] = ps[c] + diff[c];

    int s = t >> 4, q = t & 15;
#pragma unroll
    for (int c = 0; c < C_; ++c) {
        int lo = c - 12, hi = c + 12;
        float sum = ps[(hi < 31 ? hi : 31) + 1] - ps[lo > 0 ? lo : 0];
        if (lo < 0)  sum += (float)(-lo)     * diff[0];
        if (hi > 31) sum += (float)(hi - 31) * diff[31];
        float mean = sum * (1.0f / 25.0f);
        size_t idx = ((size_t)s * N_ + (size_t)(b * C_ + c)) * SEG_ + q;
        xt_seg[idx] = mean;
        xs_seg[idx] = diff[c] - mean;
    }
}

// ---------------------------------------------------------------------------
// emb batch: emb_buf[sl][gru][n][512] f16 = relu(xseg @ W_emb^T + b_emb)
// thread owns 4 consecutive k (f16x4 stores) x 32 rows.
// ---------------------------------------------------------------------------
__global__ __launch_bounds__(256) void emb_kernel(
    const float* __restrict__ xs_seg, const float* __restrict__ xt_seg,
    const float* __restrict__ W_emb, const float* __restrict__ b_emb,
    _Float16* __restrict__ emb_buf, int s0) {
    int bid = blockIdx.x;
    int gru = bid >> 8, sl = (bid >> 4) & 15, nch = bid & 15;
    int step = s0 + sl, n0 = nch * 64;
    const float* xseg = gru ? xt_seg : xs_seg;
    __shared__ float xl[64 * 16];
    int tid = threadIdx.x;
    const float* src = xseg + ((size_t)step * N_ + n0) * SEG_;
    for (int i = tid; i < 1024; i += 256) xl[i] = src[i];

    int kg = tid & 127;   // 4-k group
    int rh = tid >> 7;    // row half
    float w[4][16], bb[4];
#pragma unroll
    for (int i = 0; i < 4; ++i) {
        int k = kg * 4 + i;
        const float4* wr = (const float4*)(W_emb + (size_t)k * 16);
#pragma unroll
        for (int v = 0; v < 4; ++v) {
            float4 tt = wr[v];
            w[i][v * 4 + 0] = tt.x; w[i][v * 4 + 1] = tt.y;
            w[i][v * 4 + 2] = tt.z; w[i][v * 4 + 3] = tt.w;
        }
        bb[i] = b_emb[k];
    }
    __syncthreads();
    _Float16* dst = emb_buf + ((size_t)(sl * 2 + gru) * N_ + n0) * D_ + kg * 4;
    for (int r = 0; r < 32; ++r) {
        int row = rh * 32 + r;
        float a0 = bb[0], a1 = bb[1], a2 = bb[2], a3 = bb[3];
#pragma unroll
        for (int q = 0; q < 16; ++q) {
            float xv = xl[row * 16 + q];
            a0 = fmaf(xv, w[0][q], a0);
            a1 = fmaf(xv, w[1][q], a1);
            a2 = fmaf(xv, w[2][q], a2);
            a3 = fmaf(xv, w[3][q], a3);
        }
        f16x4 v;
        v[0] = (_Float16)(a0 > 0.f ? a0 : 0.f);
        v[1] = (_Float16)(a1 > 0.f ? a1 : 0.f);
        v[2] = (_Float16)(a2 > 0.f ? a2 : 0.f);
        v[3] = (_Float16)(a3 > 0.f ? a3 : 0.f);
        *(f16x4*)(dst + (size_t)row * D_) = v;
    }
}

// ---------------------------------------------------------------------------
// pack Wih -> [gru][kt 16][gc 1536][32 k] f16, gc = jg*48 + gate*16 + jl
// ---------------------------------------------------------------------------
__global__ __launch_bounds__(256) void pack_wih_kernel(
    const float* __restrict__ Wih_s, const float* __restrict__ Wih_t,
    _Float16* __restrict__ wp) {
    int e = blockIdx.x * 256 + threadIdx.x;     // 2*16*1536*32
    int kk = e & 31;
    int t = e >> 5;
    int gc = t % 1536;
    int t2 = t / 1536;
    int kt = t2 & 15, gru = t2 >> 4;
    int jg = gc / 48, r48 = gc % 48;
    int gate = r48 >> 4, jl = r48 & 15;
    int j = jg * 16 + jl, k = kt * 32 + kk;
    const float* W = gru ? Wih_t : Wih_s;
    wp[e] = (_Float16)W[(size_t)(gate * 512 + j) * 512 + k];
}

// ---------------------------------------------------------------------------
// pack Whh pre-swizzled for step kernel: [gru][Nt 16][kt 8][chunk 768][8 f16]
// ---------------------------------------------------------------------------
__global__ __launch_bounds__(256) void pack_whh3_kernel(
    const float* __restrict__ Whh_s, const float* __restrict__ Whh_t,
    _Float16* __restrict__ wp) {
    int e = blockIdx.x * 256 + threadIdx.x;     // 2*16*8*768*8 = 1572864
    int fi = e & 7;
    int t = e >> 3;
    int c = t % 768;
    int t2 = t / 768;
    int kt = t2 & 7;
    int Nt = (t2 >> 3) & 15;
    int gru = t2 >> 7;
    int gc = c >> 3, qs = c & 7;
    int q = qs ^ (gc & 7);
    int k = kt * 64 + q * 8 + fi;
    int jgl = gc / 48, r48 = gc % 48;
    int gate = r48 >> 4, jl = r48 & 15;
    int j = (Nt * 2 + jgl) * 16 + jl;
    const float* W = gru ? Whh_t : Whh_s;
    wp[e] = (_Float16)W[(size_t)(gate * 512 + j) * 512 + k];
}

// pe[gru][n][512] f16
__global__ __launch_bounds__(256) void pack_pe_kernel(
    const float* __restrict__ pos_s, const float* __restrict__ ch_s,
    const float* __restrict__ pos_t, const float* __restrict__ ch_t,
    _Float16* __restrict__ pe) {
    int e = blockIdx.x * 256 + threadIdx.x;     // 2*1024*512
    int k = e & 511;
    int n = (e >> 9) & 1023;
    int gru = e >> 19;
    int c = n & 31;
    const float* pos = gru ? pos_t : pos_s;
    const float* ch  = gru ? ch_t  : ch_s;
    float v = (k < 256) ? pos[k] : ch[c * 256 + (k - 256)];
    pe[e] = (_Float16)v;
}

// ---------------------------------------------------------------------------
// gi GEMM, ping-pong pipelined. Output layout: [sl][gru][sNt 16][row 1024][96]
// (step-kernel friendly). Mt = x&7 pins XCD; tile 128M x 256gc, K=512.
// ---------------------------------------------------------------------------
__global__ __launch_bounds__(512) void gi_gemm_kernel(
    const _Float16* __restrict__ emb, const _Float16* __restrict__ pe,
    const _Float16* __restrict__ wih_pack,
    _Float16* __restrict__ gi, _Float16* __restrict__ gi_pe, int mode) {
    __shared__ __align__(16) char sA[2][8192];
    __shared__ __align__(16) char sB[2][16384];
    int Mt = blockIdx.x & 7, Nt = blockIdx.x >> 3;
    int sl = blockIdx.y, gru = blockIdx.z;
    int tid = threadIdx.x, w = tid >> 6, lane = tid & 63;
    int wm = w & 3, wn = w >> 2, ml = lane & 15, qq = lane >> 4;

    const char* Ab = mode ? (const char*)(pe  + (size_t)gru * N_ * D_)
                          : (const char*)(emb + (size_t)(sl * 2 + gru) * N_ * D_);
    const char* Bb = (const char*)wih_pack + (size_t)(gru * 16) * 1536 * 64;
    _Float16* ob = mode ? gi_pe + (size_t)gru * 16 * 1024 * 96
                        : gi    + (size_t)(sl * 2 + gru) * 16 * 1024 * 96;

    int cA = tid;
    int rA = cA >> 2, kqA = (cA & 3) ^ ((rA >> 1) & 3);
    const char* gA = Ab + (size_t)(Mt * 128 + rA) * 1024 + kqA * 16;
    int cB0 = tid, cB1 = 512 + tid;
    int rB0 = cB0 >> 2, kqB0 = (cB0 & 3) ^ ((rB0 >> 1) & 3);
    int rB1 = cB1 >> 2, kqB1 = (cB1 & 3) ^ ((rB1 >> 1) & 3);
    const char* gB0 = Bb + (size_t)Nt * 16384 + rB0 * 64 + kqB0 * 16;
    const char* gB1 = Bb + (size_t)Nt * 16384 + rB1 * 64 + kqB1 * 16;

    int offA[2], offB[8];
#pragma unroll
    for (int mf = 0; mf < 2; ++mf) {
        int row = wm * 32 + mf * 16 + ml;
        offA[mf] = (row * 4 + (qq ^ ((row >> 1) & 3))) * 16;
    }
#pragma unroll
    for (int nf = 0; nf < 8; ++nf) {
        int gc = wn * 128 + nf * 16 + ml;
        offB[nf] = (gc * 4 + (qq ^ ((gc >> 1) & 3))) * 16;
    }

    f32x4 acc[2][8];
#pragma unroll
    for (int i = 0; i < 2; ++i)
#pragma unroll
        for (int nf = 0; nf < 8; ++nf) {
            f32x4 z = {0.f, 0.f, 0.f, 0.f};
            acc[i][nf] = z;
        }

    // prologue: kt=0 into buf 0
    stage16(gA, sA[0] + w * 1024);
    stage16(gB0, sB[0] + w * 1024);
    stage16(gB1, sB[0] + 8192 + w * 1024);

    for (int kt = 0; kt < 16; ++kt) {
        __syncthreads();
        if (kt < 15) {
            int nb = (kt + 1) & 1;
            stage16(gA + (kt + 1) * 64, sA[nb] + w * 1024);
            stage16(gB0 + (size_t)(kt + 1) * 98304, sB[nb] + w * 1024);
            stage16(gB1 + (size_t)(kt + 1) * 98304, sB[nb] + 8192 + w * 1024);
            asm volatile("s_waitcnt vmcnt(3)" ::: "memory");
        } else {
            asm volatile("s_waitcnt vmcnt(0)" ::: "memory");
        }
        __syncthreads();
        int cb = kt & 1;
        f16x8 a0 = *(const f16x8*)(sA[cb] + offA[0]);
        f16x8 a1 = *(const f16x8*)(sA[cb] + offA[1]);
#pragma unroll
        for (int nf = 0; nf < 8; ++nf) {
            f16x8 b = *(const f16x8*)(sB[cb] + offB[nf]);
            acc[0][nf] = __builtin_amdgcn_mfma_f32_16x16x32_f16(a0, b, acc[0][nf], 0, 0, 0);
            acc[1][nf] = __builtin_amdgcn_mfma_f32_16x16x32_f16(a1, b, acc[1][nf], 0, 0, 0);
        }
    }

#pragma unroll
    for (int nf = 0; nf < 8; ++nf) {
        int gcg = Nt * 256 + wn * 128 + nf * 16 + ml;
        int sNt = gcg / 96;
        int r96 = gcg - sNt * 96;
        _Float16* obn = ob + (size_t)sNt * 1024 * 96 + r96;
#pragma unroll
        for (int mf = 0; mf < 2; ++mf)
#pragma unroll
            for (int reg = 0; reg < 4; ++reg) {
                int row_g = Mt * 128 + wm * 32 + mf * 16 + qq * 4 + reg;
                obn[(size_t)row_g * 96] = (_Float16)acc[mf][nf][reg];
            }
    }
}

// ---------------------------------------------------------------------------
// One recurrent GRU step, ping-pong pipelined, gi prefetched to LDS.
// grid (16 Nt, 16 Mt, 2 gru) = 512 blocks. Tile 64M x 96gc, BK=64.
// ---------------------------------------------------------------------------
__global__ __launch_bounds__(256) void gru_step_mfma(
    const _Float16* __restrict__ whh_pk3,   // [gru][Nt16][kt8][768 chunks][8]
    const _Float16* __restrict__ gi_step,   // [gru][sNt16][1024 row][96]
    const float* __restrict__ bih_s, const float* __restrict__ bhh_s,
    const float* __restrict__ bih_t, const float* __restrict__ bhh_t,
    const _Float16* __restrict__ hbf_in, _Float16* __restrict__ hbf_out) {
    __shared__ __align__(16) char sA[2][8192];
    __shared__ __align__(16) char sB[2][12288];
    __shared__ __align__(16) char sGI[12288];
    int Nt = blockIdx.x, Mt = blockIdx.y, gru = blockIdx.z;
    int tid = threadIdx.x, w = tid >> 6, lane = tid & 63;
    int ml = lane & 15, qq = lane >> 4;

    const char* hinB   = (const char*)hbf_in + ((size_t)gru * N_ + Mt * 64) * 1024;
    const char* BbL    = (const char*)whh_pk3 + (size_t)(gru * 16 + Nt) * 8 * 12288
                         + lane * 16;
    const char* giSlab = (const char*)gi_step
                         + ((size_t)((gru * 16 + Nt) * 1024) + Mt * 64) * 192;

    // A staging chunks (XOR-8 swizzle preserved from R5)
    int c0 = w * 64 + lane, c1 = c0 + 256;
    int rA0 = c0 >> 3, qA0 = (c0 & 7) ^ (rA0 & 7);
    int rA1 = c1 >> 3, qA1 = (c1 & 7) ^ (rA1 & 7);
    const char* gA0 = hinB + rA0 * 1024 + qA0 * 16;
    const char* gA1 = hinB + rA1 * 1024 + qA1 * 16;

    // fragment offsets
    int rowA = w * 16 + ml;
    int offA0 = rowA * 128 + ((qq)     ^ (ml & 7)) * 16;
    int offA1 = rowA * 128 + ((4 + qq) ^ (ml & 7)) * 16;
    int offB[6][2];
#pragma unroll
    for (int g = 0; g < 6; ++g) {
        int gc = g * 16 + ml;
#pragma unroll
        for (int f = 0; f < 2; ++f)
            offB[g][f] = gc * 128 + ((f * 4 + qq) ^ (gc & 7)) * 16;
    }

    f32x4 acc[6];
#pragma unroll
    for (int g = 0; g < 6; ++g) {
        f32x4 z = {0.f, 0.f, 0.f, 0.f};
        acc[g] = z;
    }

    // prologue: gi slab (3) + kt=0 (5)
    {
        const char* gg = giSlab + w * 1024 + lane * 16;
        stage16(gg,        sGI + w * 1024);
        stage16(gg + 4096, sGI + 4096 + w * 1024);
        stage16(gg + 8192, sGI + 8192 + w * 1024);
        stage16(gA0, sA[0] + w * 1024);
        stage16(gA1, sA[0] + 4096 + w * 1024);
        const char* Bk = BbL + w * 1024;
        stage16(Bk,        sB[0] + w * 1024);
        stage16(Bk + 4096, sB[0] + 4096 + w * 1024);
        stage16(Bk + 8192, sB[0] + 8192 + w * 1024);
    }

    for (int kt = 0; kt < 8; ++kt) {
        __syncthreads();
        if (kt < 7) {
            int nb = (kt + 1) & 1;
            stage16(gA0 + (kt + 1) * 128, sA[nb] + w * 1024);
            stage16(gA1 + (kt + 1) * 128, sA[nb] + 4096 + w * 1024);
            const char* Bk = BbL + (kt + 1) * 12288 + w * 1024;
            stage16(Bk,        sB[nb] + w * 1024);
            stage16(Bk + 4096, sB[nb] + 4096 + w * 1024);
            stage16(Bk + 8192, sB[nb] + 8192 + w * 1024);
            asm volatile("s_waitcnt vmcnt(5)" ::: "memory");
        } else {
            asm volatile("s_waitcnt vmcnt(0)" ::: "memory");
        }
        __syncthreads();
        int cb = kt & 1;
        f16x8 a0 = *(const f16x8*)(sA[cb] + offA0);
        f16x8 a1 = *(const f16x8*)(sA[cb] + offA1);
#pragma unroll
        for (int g = 0; g < 6; ++g) {
            f16x8 b0 = *(const f16x8*)(sB[cb] + offB[g][0]);
            acc[g] = __builtin_amdgcn_mfma_f32_16x16x32_f16(a0, b0, acc[g], 0, 0, 0);
            f16x8 b1 = *(const f16x8*)(sB[cb] + offB[g][1]);
            acc[g] = __builtin_amdgcn_mfma_f32_16x16x32_f16(a1, b1, acc[g], 0, 0, 0);
        }
    }

    const float* bi = gru ? bih_t : bih_s;
    const float* bh = gru ? bhh_t : bhh_s;
    const _Float16* sgi = (const _Float16*)sGI;
    int rl0 = w * 16 + qq * 4;
#pragma unroll
    for (int jgl = 0; jgl < 2; ++jgl) {
        int j = (Nt * 2 + jgl) * 16 + ml;
        float bir = bi[j], biz = bi[D_ + j], bin = bi[2 * D_ + j];
        float bhr = bh[j], bhz = bh[D_ + j], bhn = bh[2 * D_ + j];
#pragma unroll
        for (int reg = 0; reg < 4; ++reg) {
            int rowL = rl0 + reg;
            int row = Mt * 64 + rowL;
            float gr = (float)sgi[rowL * 96 + jgl * 48 + ml];
            float gz = (float)sgi[rowL * 96 + jgl * 48 + 16 + ml];
            float gn = (float)sgi[rowL * 96 + jgl * 48 + 32 + ml];
            size_t idx = ((size_t)gru * N_ + row) * D_ + j;
            float r = 1.f / (1.f + __expf(-(acc[jgl * 3 + 0][reg] + gr + bir + bhr)));
            float z = 1.f / (1.f + __expf(-(acc[jgl * 3 + 1][reg] + gz + biz + bhz)));
            float nn = tanhf(gn + bin + r * (acc[jgl * 3 + 2][reg] + bhn));
            float hp = (float)hbf_in[idx];
            float hv = (1.f - z) * nn + z * hp;
            hbf_out[idx] = (_Float16)hv;
        }
    }
}

// ---------------------------------------------------------------------------
__global__ __launch_bounds__(256) void head_kernel(
    const _Float16* __restrict__ hs2, const _Float16* __restrict__ ht2,
    const float* __restrict__ Wps, const float* __restrict__ bps,
    const float* __restrict__ Wpt, const float* __restrict__ bpt,
    const float* __restrict__ x, float* __restrict__ out) {
    int g = blockIdx.x * 256 + threadIdx.x;
    int n = g >> 4, p = g & 15;
    int b = n >> 5, c = n & 31;
    const _Float16* hs = hs2 + (size_t)n * D_;
    const _Float16* ht = ht2 + (size_t)n * D_;
    const float* ws = Wps + (size_t)p * D_;
    const float* wt = Wpt + (size_t)p * D_;
    float acc = bps[p] + bpt[p];
    for (int k = 0; k < D_; ++k)
        acc += (float)hs[k] * ws[k] + (float)ht[k] * wt[k];
    float last = x[((size_t)b * L_ + (L_ - 1)) * C_ + c];
    out[((size_t)b * SEG_ + p) * C_ + c] = acc + last;
}

// ---------------------------------------------------------------------------
extern "C" void kernel_launch(void* const* d_in, const int* in_sizes, int n_in,
                              void* d_out, int out_size, void* d_ws, size_t ws_size,
                              hipStream_t stream) {
    const float* x     = (const float*)d_in[0];
    const float* W_emb = (const float*)d_in[1];
    const float* b_emb = (const float*)d_in[2];
    const float* Wih_s = (const float*)d_in[3];
    const float* Whh_s = (const float*)d_in[4];
    const float* bih_s = (const float*)d_in[5];
    const float* bhh_s = (const float*)d_in[6];
    const float* Wih_t = (const float*)d_in[7];
    const float* Whh_t = (const float*)d_in[8];
    const float* bih_t = (const float*)d_in[9];
    const float* bhh_t = (const float*)d_in[10];
    const float* pos_s = (const float*)d_in[11];
    const float* ch_s  = (const float*)d_in[12];
    const float* pos_t = (const float*)d_in[13];
    const float* ch_t  = (const float*)d_in[14];
    const float* Wps   = (const float*)d_in[15];
    const float* bps   = (const float*)d_in[16];
    const float* Wpt   = (const float*)d_in[17];
    const float* bpt   = (const float*)d_in[18];
    float* out = (float*)d_out;

    char* p = (char*)d_ws;
    float* xs_seg = (float*)p;          p += (size_t)SX_ * N_ * SEG_ * 4;       // 4 MB
    float* xt_seg = (float*)p;          p += (size_t)SX_ * N_ * SEG_ * 4;       // 4 MB
    _Float16* emb_buf = (_Float16*)p;   p += (size_t)16 * 2 * N_ * D_ * 2;      // 32 MB
    _Float16* gi_buf  = (_Float16*)p;   p += (size_t)16 * 2 * 16 * 1024 * 96 * 2; // 96 MB
    _Float16* gi_pe   = (_Float16*)p;   p += (size_t)2 * 16 * 1024 * 96 * 2;    // 6 MB
    _Float16* pe_buf  = (_Float16*)p;   p += (size_t)2 * N_ * D_ * 2;           // 2 MB
    _Float16* wih_pk  = (_Float16*)p;   p += (size_t)2 * 16 * 1536 * 32 * 2;    // 3 MB
    _Float16* whh_pk3 = (_Float16*)p;   p += (size_t)2 * 16 * 8 * 768 * 8 * 2;  // 3 MB
    _Float16* hbf0 = (_Float16*)p;      p += (size_t)2 * N_ * D_ * 2;           // 2 MB
    _Float16* hbf1 = (_Float16*)p;      p += (size_t)2 * N_ * D_ * 2;           // 2 MB

    hipMemsetAsync(hbf0, 0, (size_t)2 * N_ * D_ * 2, stream);

    pack_wih_kernel<<<6144, 256, 0, stream>>>(Wih_s, Wih_t, wih_pk);
    pack_whh3_kernel<<<6144, 256, 0, stream>>>(Whh_s, Whh_t, whh_pk3);
    pack_pe_kernel<<<4096, 256, 0, stream>>>(pos_s, ch_s, pos_t, ch_t, pe_buf);
    prep_kernel<<<B_ * 4, 256, 0, stream>>>(x, xs_seg, xt_seg);

    dim3 sgrid(16, 16, 2);
    size_t gi_sl_stride = (size_t)2 * 16 * 1024 * 96;
    for (int b = 0; b < 4; ++b) {
        emb_kernel<<<512, 256, 0, stream>>>(xs_seg, xt_seg, W_emb, b_emb, emb_buf, b * 16);
        gi_gemm_kernel<<<dim3(48, 16, 2), 512, 0, stream>>>(
            emb_buf, pe_buf, wih_pk, gi_buf, gi_pe, 0);
        for (int sl = 0; sl < 16; ++sl) {
            int it = b * 16 + sl;
            const _Float16* hbin = (it & 1) ? hbf1 : hbf0;
            _Float16* hbout      = (it & 1) ? hbf0 : hbf1;
            gru_step_mfma<<<sgrid, 256, 0, stream>>>(
                whh_pk3, gi_buf + (size_t)sl * gi_sl_stride,
                bih_s, bhh_s, bih_t, bhh_t, hbin, hbout);
        }
    }
    // decoder: gi from pe; state in *0 -> write *1
    gi_gemm_kernel<<<dim3(48, 1, 2), 512, 0, stream>>>(
        emb_buf, pe_buf, wih_pk, gi_buf, gi_pe, 1);
    gru_step_mfma<<<sgrid, 256, 0, stream>>>(
        whh_pk3, gi_pe, bih_s, bhh_s, bih_t, bhh_t, hbf0, hbf1);

    head_kernel<<<N_ * SEG_ / 256, 256, 0, stream>>>(
        hbf1, hbf1 + (size_t)N_ * D_, Wps, bps, Wpt, bpt, x, out);
}

// Round 7
// 1093.343 us; speedup vs baseline: 1.1154x; 1.1154x over previous
//
#include <hip/hip_runtime.h>
#include <math.h>

#define B_   32
#define L_   1024
#define C_   32
#define D_   512
#define SEG_ 16
#define SX_  64
#define N_   1024   // B*C

typedef _Float16 f16x8 __attribute__((ext_vector_type(8)));
typedef _Float16 f16x4 __attribute__((ext_vector_type(4)));
typedef float    f32x4 __attribute__((ext_vector_type(4)));

__device__ __forceinline__ void stage16(const void* g, void* l) {
    __builtin_amdgcn_global_load_lds((const __attribute__((address_space(1))) void*)g,
                                     (__attribute__((address_space(3))) void*)l, 16, 0, 0);
}
// sc0|sc1 (cpol 1|16): device-coherent direct-to-coherence-point (cross-XCD safe)
__device__ __forceinline__ void stage16c(const void* g, void* l) {
    __builtin_amdgcn_global_load_lds((const __attribute__((address_space(1))) void*)g,
                                     (__attribute__((address_space(3))) void*)l, 16, 0, 17);
}
__device__ __forceinline__ void store_h16(void* p, float v) {
    _Float16 h = (_Float16)v;
    unsigned short us;
    __builtin_memcpy(&us, &h, 2);
    unsigned int uu = us;
    asm volatile("global_store_short %0, %1, off sc0 sc1" :: "v"(p), "v"(uu) : "memory");
}

// ---------------------------------------------------------------------------
// prep: x (B,L,C) -> xs_seg, xt_seg fp32 (step, n, seg); channel-axis moving
// mean (reference semantics), window 25, edge replication.
// ---------------------------------------------------------------------------
__global__ __launch_bounds__(256) void prep_kernel(const float* __restrict__ x,
                                                   float* __restrict__ xs_seg,
                                                   float* __restrict__ xt_seg) {
    int b = blockIdx.x >> 2;
    int t = ((blockIdx.x & 3) << 8) + threadIdx.x;
    const float* xb    = x + (size_t)b * (L_ * C_);
    const float* xrow  = xb + (size_t)t * C_;
    const float* xlast = xb + (size_t)(L_ - 1) * C_;

    float diff[C_];
#pragma unroll
    for (int c = 0; c < C_; ++c) diff[c] = xrow[c] - xlast[c];
    float ps[C_ + 1];
    ps[0] = 0.f;
#pragma unroll
    for (int c = 0; c < C_; ++c) ps[c + 1] = ps[c] + diff[c];

    int s = t >> 4, q = t & 15;
#pragma unroll
    for (int c = 0; c < C_; ++c) {
        int lo = c - 12, hi = c + 12;
        float sum = ps[(hi < 31 ? hi : 31) + 1] - ps[lo > 0 ? lo : 0];
        if (lo < 0)  sum += (float)(-lo)     * diff[0];
        if (hi > 31) sum += (float)(hi - 31) * diff[31];
        float mean = sum * (1.0f / 25.0f);
        size_t idx = ((size_t)s * N_ + (size_t)(b * C_ + c)) * SEG_ + q;
        xt_seg[idx] = mean;
        xs_seg[idx] = diff[c] - mean;
    }
}

// ---------------------------------------------------------------------------
// emb batch: emb_buf[sl][gru][n][512] f16 = relu(xseg @ W_emb^T + b_emb)
// ---------------------------------------------------------------------------
__global__ __launch_bounds__(256) void emb_kernel(
    const float* __restrict__ xs_seg, const float* __restrict__ xt_seg,
    const float* __restrict__ W_emb, const float* __restrict__ b_emb,
    _Float16* __restrict__ emb_buf, int s0) {
    int bid = blockIdx.x;
    int gru = bid >> 8, sl = (bid >> 4) & 15, nch = bid & 15;
    int step = s0 + sl, n0 = nch * 64;
    const float* xseg = gru ? xt_seg : xs_seg;
    __shared__ float xl[64 * 16];
    int tid = threadIdx.x;
    const float* src = xseg + ((size_t)step * N_ + n0) * SEG_;
    for (int i = tid; i < 1024; i += 256) xl[i] = src[i];

    int kg = tid & 127;
    int rh = tid >> 7;
    float w[4][16], bb[4];
#pragma unroll
    for (int i = 0; i < 4; ++i) {
        int k = kg * 4 + i;
        const float4* wr = (const float4*)(W_emb + (size_t)k * 16);
#pragma unroll
        for (int v = 0; v < 4; ++v) {
            float4 tt = wr[v];
            w[i][v * 4 + 0] = tt.x; w[i][v * 4 + 1] = tt.y;
            w[i][v * 4 + 2] = tt.z; w[i][v * 4 + 3] = tt.w;
        }
        bb[i] = b_emb[k];
    }
    __syncthreads();
    _Float16* dst = emb_buf + ((size_t)(sl * 2 + gru) * N_ + n0) * D_ + kg * 4;
    for (int r = 0; r < 32; ++r) {
        int row = rh * 32 + r;
        float a0 = bb[0], a1 = bb[1], a2 = bb[2], a3 = bb[3];
#pragma unroll
        for (int q = 0; q < 16; ++q) {
            float xv = xl[row * 16 + q];
            a0 = fmaf(xv, w[0][q], a0);
            a1 = fmaf(xv, w[1][q], a1);
            a2 = fmaf(xv, w[2][q], a2);
            a3 = fmaf(xv, w[3][q], a3);
        }
        f16x4 v;
        v[0] = (_Float16)(a0 > 0.f ? a0 : 0.f);
        v[1] = (_Float16)(a1 > 0.f ? a1 : 0.f);
        v[2] = (_Float16)(a2 > 0.f ? a2 : 0.f);
        v[3] = (_Float16)(a3 > 0.f ? a3 : 0.f);
        *(f16x4*)(dst + (size_t)row * D_) = v;
    }
}

// ---------------------------------------------------------------------------
// pack Wih -> [gru][kt 16][gc 1536][32 k] f16, gc = jg*48 + gate*16 + jl
// ---------------------------------------------------------------------------
__global__ __launch_bounds__(256) void pack_wih_kernel(
    const float* __restrict__ Wih_s, const float* __restrict__ Wih_t,
    _Float16* __restrict__ wp) {
    int e = blockIdx.x * 256 + threadIdx.x;     // 2*16*1536*32
    int kk = e & 31;
    int t = e >> 5;
    int gc = t % 1536;
    int t2 = t / 1536;
    int kt = t2 & 15, gru = t2 >> 4;
    int jg = gc / 48, r48 = gc % 48;
    int gate = r48 >> 4, jl = r48 & 15;
    int j = jg * 16 + jl, k = kt * 32 + kk;
    const float* W = gru ? Wih_t : Wih_s;
    wp[e] = (_Float16)W[(size_t)(gate * 512 + j) * 512 + k];
}

// ---------------------------------------------------------------------------
// pack Whh for chain kernel: [gru][member 8][kt 8][chunk 1536][8 f16]
// chunk c: gc = c>>3, qs = c&7, q = qs ^ (gc&7); k = kt*64 + q*8 + fi;
// gc = jg4*48 + gate*16 + jl, j = (member*4 + jg4)*16 + jl. Linear staging,
// LDS ends up XOR-8 swizzled for free.
// ---------------------------------------------------------------------------
__global__ __launch_bounds__(256) void pack_whh4_kernel(
    const float* __restrict__ Whh_s, const float* __restrict__ Whh_t,
    _Float16* __restrict__ wp) {
    int e = blockIdx.x * 256 + threadIdx.x;     // 2*8*8*1536*8 = 1572864
    int fi = e & 7;
    int t = e >> 3;
    int c = t % 1536;
    int t2 = t / 1536;
    int kt = t2 & 7;
    int t3 = t2 >> 3;
    int member = t3 & 7, gru = t3 >> 3;
    int gc = c >> 3, qs = c & 7;
    int q = qs ^ (gc & 7);
    int k = kt * 64 + q * 8 + fi;
    int jg4 = gc / 48, r48 = gc % 48;
    int gate = r48 >> 4, jl = r48 & 15;
    int j = (member * 4 + jg4) * 16 + jl;
    const float* W = gru ? Whh_t : Whh_s;
    wp[e] = (_Float16)W[(size_t)(gate * 512 + j) * 512 + k];
}

// pe[gru][n][512] f16
__global__ __launch_bounds__(256) void pack_pe_kernel(
    const float* __restrict__ pos_s, const float* __restrict__ ch_s,
    const float* __restrict__ pos_t, const float* __restrict__ ch_t,
    _Float16* __restrict__ pe) {
    int e = blockIdx.x * 256 + threadIdx.x;     // 2*1024*512
    int k = e & 511;
    int n = (e >> 9) & 1023;
    int gru = e >> 19;
    int c = n & 31;
    const float* pos = gru ? pos_t : pos_s;
    const float* ch  = gru ? ch_t  : ch_s;
    float v = (k < 256) ? pos[k] : ch[c * 256 + (k - 256)];
    pe[e] = (_Float16)v;
}

// ---------------------------------------------------------------------------
// gi GEMM (R5 structure). Output layout: [sl][gru][member 8][row 1024][192]
// (chain-kernel slab-contiguous). Mt = x&7 pins XCD for B-residency.
// ---------------------------------------------------------------------------
__global__ __launch_bounds__(512, 2) void gi_gemm_kernel(
    const _Float16* __restrict__ emb, const _Float16* __restrict__ pe,
    const _Float16* __restrict__ wih_pack,
    _Float16* __restrict__ gi, _Float16* __restrict__ gi_pe, int mode) {
    __shared__ __align__(16) char sA[8192];
    __shared__ __align__(16) char sB[16384];
    int Mt = blockIdx.x & 7, Nt = blockIdx.x >> 3;
    int sl = blockIdx.y, gru = blockIdx.z;
    int tid = threadIdx.x, w = tid >> 6, lane = tid & 63;
    int wm = w & 3, wn = w >> 2, ml = lane & 15, qq = lane >> 4;

    const char* Ab = mode ? (const char*)(pe  + (size_t)gru * N_ * D_)
                          : (const char*)(emb + (size_t)(sl * 2 + gru) * N_ * D_);
    const char* Bb = (const char*)wih_pack + (size_t)(gru * 16) * 1536 * 64;

    int cA = tid;
    int rA = cA >> 2, kqA = (cA & 3) ^ ((rA >> 1) & 3);
    const char* gA = Ab + (size_t)(Mt * 128 + rA) * 1024 + kqA * 16;
    int cB0 = tid, cB1 = 512 + tid;
    int rB0 = cB0 >> 2, kqB0 = (cB0 & 3) ^ ((rB0 >> 1) & 3);
    int rB1 = cB1 >> 2, kqB1 = (cB1 & 3) ^ ((rB1 >> 1) & 3);

    int offA[2], offB[8];
#pragma unroll
    for (int mf = 0; mf < 2; ++mf) {
        int row = wm * 32 + mf * 16 + ml;
        offA[mf] = (row * 4 + (qq ^ ((row >> 1) & 3))) * 16;
    }
#pragma unroll
    for (int nf = 0; nf < 8; ++nf) {
        int gc = wn * 128 + nf * 16 + ml;
        offB[nf] = (gc * 4 + (qq ^ ((gc >> 1) & 3))) * 16;
    }

    f32x4 acc[2][8];
#pragma unroll
    for (int i = 0; i < 2; ++i)
#pragma unroll
        for (int nf = 0; nf < 8; ++nf) {
            f32x4 z = {0.f, 0.f, 0.f, 0.f};
            acc[i][nf] = z;
        }

    for (int kt = 0; kt < 16; ++kt) {
        __syncthreads();
        stage16(gA + kt * 64, sA + w * 1024);
        const char* Bkt = Bb + (size_t)kt * 98304 + (size_t)Nt * 16384;
        stage16(Bkt + rB0 * 64 + kqB0 * 16, sB + w * 1024);
        stage16(Bkt + rB1 * 64 + kqB1 * 16, sB + 8192 + w * 1024);
        asm volatile("s_waitcnt vmcnt(0)" ::: "memory");
        __syncthreads();
        f16x8 a0 = *(const f16x8*)(sA + offA[0]);
        f16x8 a1 = *(const f16x8*)(sA + offA[1]);
#pragma unroll
        for (int nf = 0; nf < 8; ++nf) {
            f16x8 b = *(const f16x8*)(sB + offB[nf]);
            acc[0][nf] = __builtin_amdgcn_mfma_f32_16x16x32_f16(a0, b, acc[0][nf], 0, 0, 0);
            acc[1][nf] = __builtin_amdgcn_mfma_f32_16x16x32_f16(a1, b, acc[1][nf], 0, 0, 0);
        }
    }

    _Float16* slabBase = (mode ? gi_pe : gi + (size_t)sl * 2 * 8 * 1024 * 192)
                         + (size_t)gru * 8 * 1024 * 192;
#pragma unroll
    for (int nf = 0; nf < 8; ++nf) {
        int gcg = Nt * 256 + wn * 128 + nf * 16 + ml;
        int member = gcg / 192, r192 = gcg % 192;
        _Float16* obn = slabBase + (size_t)member * 1024 * 192 + r192;
#pragma unroll
        for (int mf = 0; mf < 2; ++mf)
#pragma unroll
            for (int reg = 0; reg < 4; ++reg) {
                int row_g = Mt * 128 + wm * 32 + mf * 16 + qq * 4 + reg;
                obn[(size_t)row_g * 192] = (_Float16)acc[mf][nf][reg];
            }
    }
}

// ---------------------------------------------------------------------------
// Persistent chain scan: 256 blocks (1/CU, all co-resident) of 512 threads.
// 32 independent chains (Mt 16 x gru 2), 8 members each; member owns
// 64 rows x 192 gc. Per step: gh = h @ Whh slice (BK=64, 8 iters, dbuf),
// fused GRU epilogue (hp carried in registers), h exchanged via sc0/sc1
// coherence-point ops, per-chain 8-wide monotone atomic barrier.
// ---------------------------------------------------------------------------
__global__ __launch_bounds__(512, 2) void gru_chain_kernel(
    const _Float16* __restrict__ whh_pk4,  // [gru][m8][kt8][1536][8]
    const _Float16* __restrict__ gi_base,  // [sl][gru][m8][1024][192]
    const float* __restrict__ bih_s, const float* __restrict__ bhh_s,
    const float* __restrict__ bih_t, const float* __restrict__ bhh_t,
    _Float16* __restrict__ hbf0, _Float16* __restrict__ hbf1,
    unsigned* __restrict__ flags, int nsteps, int sbase) {
    __shared__ __align__(16) char sA[2][8192];
    __shared__ __align__(16) char sB[2][24576];
    __shared__ __align__(16) char sGI[24576];
    int bid = blockIdx.x;
    int member = bid & 7, chain = bid >> 3;
    int Mt = chain & 15, gru = chain >> 4;
    int tid = threadIdx.x, w = tid >> 6, lane = tid & 63;
    int ml = lane & 15, qq = lane >> 4;
    int wm = w & 3, wn = w >> 2;

    const char* Bb = (const char*)whh_pk4 + (size_t)(gru * 8 + member) * 8 * 24576;
    const char* h0 = (const char*)hbf0 + ((size_t)gru * N_ + Mt * 64) * 1024;
    const char* h1 = (const char*)hbf1 + ((size_t)gru * N_ + Mt * 64) * 1024;

    // A staging chunk for this thread (XOR-8 swizzle, 128B rows)
    int rA = tid >> 3, qA = (tid & 7) ^ (rA & 7);
    size_t aoff = (size_t)rA * 1024 + qA * 16;

    // fragment offsets
    int rowA = wm * 16 + ml;
    int offA0 = rowA * 128 + ((qq)     ^ (rowA & 7)) * 16;
    int offA1 = rowA * 128 + ((4 + qq) ^ (rowA & 7)) * 16;
    int offB[6][2];
#pragma unroll
    for (int g = 0; g < 6; ++g) {
        int gc = wn * 96 + g * 16 + ml;
#pragma unroll
        for (int f = 0; f < 2; ++f)
            offB[g][f] = gc * 128 + ((f * 4 + qq) ^ (gc & 7)) * 16;
    }

    // biases + register-resident hp
    const float* bi = gru ? bih_t : bih_s;
    const float* bh = gru ? bhh_t : bhh_s;
    int jj[2];
    float bir[2], biz[2], bin[2], bhr[2], bhz[2], bhn[2];
    float hp[2][4];
#pragma unroll
    for (int jgl = 0; jgl < 2; ++jgl) {
        int j = (member * 4 + wn * 2 + jgl) * 16 + ml;
        jj[jgl] = j;
        bir[jgl] = bi[j]; biz[jgl] = bi[D_ + j]; bin[jgl] = bi[2 * D_ + j];
        bhr[jgl] = bh[j]; bhz[jgl] = bh[D_ + j]; bhn[jgl] = bh[2 * D_ + j];
#pragma unroll
        for (int reg = 0; reg < 4; ++reg) {
            int row = Mt * 64 + wm * 16 + qq * 4 + reg;
            hp[jgl][reg] = (float)hbf0[((size_t)gru * N_ + row) * 512 + j];
        }
    }

    unsigned* flag = flags + chain * 32;

    for (int it = 0; it < nsteps; ++it) {
        int gstep = sbase + it;
        const char* hin = (gstep & 1) ? h1 : h0;
        _Float16* hout = (gstep & 1) ? hbf0 : hbf1;
        const char* giSlab = (const char*)gi_base
            + ((((size_t)it * 2 + gru) * 8 + member) * 1024 + (size_t)Mt * 64) * 384;

        f32x4 acc[6];
#pragma unroll
        for (int g = 0; g < 6; ++g) {
            f32x4 z = {0.f, 0.f, 0.f, 0.f};
            acc[g] = z;
        }

        // prologue: gi slab (3) + kt=0 A(1)+B(3)
        stage16(giSlab + tid * 16,         sGI + w * 1024);
        stage16(giSlab + tid * 16 + 8192,  sGI + 8192 + w * 1024);
        stage16(giSlab + tid * 16 + 16384, sGI + 16384 + w * 1024);
        stage16c(hin + aoff, sA[0] + w * 1024);
        stage16(Bb + tid * 16,         sB[0] + w * 1024);
        stage16(Bb + tid * 16 + 8192,  sB[0] + 8192 + w * 1024);
        stage16(Bb + tid * 16 + 16384, sB[0] + 16384 + w * 1024);

        for (int kt = 0; kt < 8; ++kt) {
            __syncthreads();
            if (kt < 7) {
                int nb = (kt + 1) & 1;
                stage16c(hin + aoff + (kt + 1) * 128, sA[nb] + w * 1024);
                const char* Bkt = Bb + (kt + 1) * 24576;
                stage16(Bkt + tid * 16,         sB[nb] + w * 1024);
                stage16(Bkt + tid * 16 + 8192,  sB[nb] + 8192 + w * 1024);
                stage16(Bkt + tid * 16 + 16384, sB[nb] + 16384 + w * 1024);
                asm volatile("s_waitcnt vmcnt(4)" ::: "memory");
            } else {
                asm volatile("s_waitcnt vmcnt(0)" ::: "memory");
            }
            __syncthreads();
            int cb = kt & 1;
            f16x8 a0 = *(const f16x8*)(sA[cb] + offA0);
            f16x8 a1 = *(const f16x8*)(sA[cb] + offA1);
#pragma unroll
            for (int g = 0; g < 6; ++g) {
                f16x8 b0 = *(const f16x8*)(sB[cb] + offB[g][0]);
                acc[g] = __builtin_amdgcn_mfma_f32_16x16x32_f16(a0, b0, acc[g], 0, 0, 0);
                f16x8 b1 = *(const f16x8*)(sB[cb] + offB[g][1]);
                acc[g] = __builtin_amdgcn_mfma_f32_16x16x32_f16(a1, b1, acc[g], 0, 0, 0);
            }
        }

        const _Float16* sgi = (const _Float16*)sGI;
#pragma unroll
        for (int jgl = 0; jgl < 2; ++jgl) {
#pragma unroll
            for (int reg = 0; reg < 4; ++reg) {
                int rowL = wm * 16 + qq * 4 + reg;
                int row = Mt * 64 + rowL;
                int gb = rowL * 192 + wn * 96 + jgl * 48 + ml;
                float gr = (float)sgi[gb];
                float gz = (float)sgi[gb + 16];
                float gn = (float)sgi[gb + 32];
                float r = 1.f / (1.f + __expf(-(acc[jgl * 3 + 0][reg] + gr + bir[jgl] + bhr[jgl])));
                float z = 1.f / (1.f + __expf(-(acc[jgl * 3 + 1][reg] + gz + biz[jgl] + bhz[jgl])));
                float nn = tanhf(gn + bin[jgl] + r * (acc[jgl * 3 + 2][reg] + bhn[jgl]));
                float hv = (1.f - z) * nn + z * hp[jgl][reg];
                hp[jgl][reg] = hv;
                store_h16(hout + ((size_t)gru * N_ + row) * 512 + jj[jgl], hv);
            }
        }

        asm volatile("s_waitcnt vmcnt(0)" ::: "memory");
        __syncthreads();
        if (tid == 0) {
            __hip_atomic_fetch_add(flag, 1u, __ATOMIC_RELAXED, __HIP_MEMORY_SCOPE_AGENT);
            if (it < nsteps - 1) {
                unsigned tgt = 8u * (unsigned)(gstep + 1);
                int guard = 0;
                while (__hip_atomic_load(flag, __ATOMIC_RELAXED, __HIP_MEMORY_SCOPE_AGENT) < tgt) {
                    __builtin_amdgcn_s_sleep(1);
                    if (++guard > (1 << 23)) break;   // bail: fail, don't hang
                }
            }
        }
        __syncthreads();
    }
}

// ---------------------------------------------------------------------------
__global__ __launch_bounds__(256) void head_kernel(
    const _Float16* __restrict__ hs2, const _Float16* __restrict__ ht2,
    const float* __restrict__ Wps, const float* __restrict__ bps,
    const float* __restrict__ Wpt, const float* __restrict__ bpt,
    const float* __restrict__ x, float* __restrict__ out) {
    int g = blockIdx.x * 256 + threadIdx.x;
    int n = g >> 4, p = g & 15;
    int b = n >> 5, c = n & 31;
    const _Float16* hs = hs2 + (size_t)n * D_;
    const _Float16* ht = ht2 + (size_t)n * D_;
    const float* ws = Wps + (size_t)p * D_;
    const float* wt = Wpt + (size_t)p * D_;
    float acc = bps[p] + bpt[p];
    for (int k = 0; k < D_; ++k)
        acc += (float)hs[k] * ws[k] + (float)ht[k] * wt[k];
    float last = x[((size_t)b * L_ + (L_ - 1)) * C_ + c];
    out[((size_t)b * SEG_ + p) * C_ + c] = acc + last;
}

// ---------------------------------------------------------------------------
extern "C" void kernel_launch(void* const* d_in, const int* in_sizes, int n_in,
                              void* d_out, int out_size, void* d_ws, size_t ws_size,
                              hipStream_t stream) {
    const float* x     = (const float*)d_in[0];
    const float* W_emb = (const float*)d_in[1];
    const float* b_emb = (const float*)d_in[2];
    const float* Wih_s = (const float*)d_in[3];
    const float* Whh_s = (const float*)d_in[4];
    const float* bih_s = (const float*)d_in[5];
    const float* bhh_s = (const float*)d_in[6];
    const float* Wih_t = (const float*)d_in[7];
    const float* Whh_t = (const float*)d_in[8];
    const float* bih_t = (const float*)d_in[9];
    const float* bhh_t = (const float*)d_in[10];
    const float* pos_s = (const float*)d_in[11];
    const float* ch_s  = (const float*)d_in[12];
    const float* pos_t = (const float*)d_in[13];
    const float* ch_t  = (const float*)d_in[14];
    const float* Wps   = (const float*)d_in[15];
    const float* bps   = (const float*)d_in[16];
    const float* Wpt   = (const float*)d_in[17];
    const float* bpt   = (const float*)d_in[18];
    float* out = (float*)d_out;

    char* p = (char*)d_ws;
    float* xs_seg = (float*)p;          p += (size_t)SX_ * N_ * SEG_ * 4;       // 4 MB
    float* xt_seg = (float*)p;          p += (size_t)SX_ * N_ * SEG_ * 4;       // 4 MB
    _Float16* emb_buf = (_Float16*)p;   p += (size_t)16 * 2 * N_ * D_ * 2;      // 32 MB
    _Float16* gi_buf  = (_Float16*)p;   p += (size_t)16 * 2 * 8 * 1024 * 192 * 2; // 96 MB
    _Float16* gi_pe   = (_Float16*)p;   p += (size_t)2 * 8 * 1024 * 192 * 2;    // 6 MB
    _Float16* pe_buf  = (_Float16*)p;   p += (size_t)2 * N_ * D_ * 2;           // 2 MB
    _Float16* wih_pk  = (_Float16*)p;   p += (size_t)2 * 16 * 1536 * 32 * 2;    // 3 MB
    _Float16* whh_pk4 = (_Float16*)p;   p += (size_t)2 * 8 * 8 * 1536 * 8 * 2;  // 3 MB
    _Float16* hbf0 = (_Float16*)p;      p += (size_t)2 * N_ * D_ * 2;           // 2 MB
    _Float16* hbf1 = (_Float16*)p;      p += (size_t)2 * N_ * D_ * 2;           // 2 MB
    unsigned* flags = (unsigned*)p;     p += 32 * 32 * 4;                       // 4 KB

    hipMemsetAsync(hbf0, 0, (size_t)2 * N_ * D_ * 2, stream);
    hipMemsetAsync(flags, 0, 32 * 32 * 4, stream);

    pack_wih_kernel<<<6144, 256, 0, stream>>>(Wih_s, Wih_t, wih_pk);
    pack_whh4_kernel<<<6144, 256, 0, stream>>>(Whh_s, Whh_t, whh_pk4);
    pack_pe_kernel<<<4096, 256, 0, stream>>>(pos_s, ch_s, pos_t, ch_t, pe_buf);
    prep_kernel<<<B_ * 4, 256, 0, stream>>>(x, xs_seg, xt_seg);

    for (int b = 0; b < 4; ++b) {
        emb_kernel<<<512, 256, 0, stream>>>(xs_seg, xt_seg, W_emb, b_emb, emb_buf, b * 16);
        gi_gemm_kernel<<<dim3(48, 16, 2), 512, 0, stream>>>(
            emb_buf, pe_buf, wih_pk, gi_buf, gi_pe, 0);
        gru_chain_kernel<<<256, 512, 0, stream>>>(
            whh_pk4, gi_buf, bih_s, bhh_s, bih_t, bhh_t,
            hbf0, hbf1, flags, 16, b * 16);
    }
    // decoder: gi from pe, one step (hbf0 -> hbf1)
    gi_gemm_kernel<<<dim3(48, 1, 2), 512, 0, stream>>>(
        emb_buf, pe_buf, wih_pk, gi_buf, gi_pe, 1);
    gru_chain_kernel<<<256, 512, 0, stream>>>(
        whh_pk4, gi_pe, bih_s, bhh_s, bih_t, bhh_t,
        hbf0, hbf1, flags, 1, 64);

    head_kernel<<<N_ * SEG_ / 256, 256, 0, stream>>>(
        hbf1, hbf1 + (size_t)N_ * D_, Wps, bps, Wpt, bpt, x, out);
}